// Round 4
// baseline (168.190 us; speedup 1.0000x reference)
//
#include <hip/hip_runtime.h>
#include <math.h>

#define NB 8192
#define ND 256
#define DELTA_F 0.2f
#define NT 24   // 3 split-terms x 8 K-tiles of 32: [Xh.Yh | Xl.Yh | Xh.Yl]

typedef __attribute__((ext_vector_type(8))) __bf16 bf16x8;
typedef __attribute__((ext_vector_type(4))) __bf16 bf16x4;
typedef __attribute__((ext_vector_type(4))) float f32x4;

__device__ __forceinline__ void gload16(const void* g, void* l) {
  __builtin_amdgcn_global_load_lds(
      (const __attribute__((address_space(1))) void*)g,
      (__attribute__((address_space(3))) void*)l, 16, 0, 0);
}

// ---- prep: wave-per-row norms, diag sim, hi/lo bf16 splits; zeroes cnt/loss ----
__global__ __launch_bounds__(256) void normalize_split_k(
    const float* __restrict__ x, const float* __restrict__ y,
    __bf16* __restrict__ Xh, __bf16* __restrict__ Xl,
    __bf16* __restrict__ Yh, __bf16* __restrict__ Yl,
    float* __restrict__ dd, float* __restrict__ loss_accum, int* __restrict__ cnt) {
  const int w = threadIdx.x >> 6, lane = threadIdx.x & 63;
  const int i = blockIdx.x * 4 + w;
  const size_t rbase = (size_t)i * ND;
  const float4 xv = *(const float4*)&x[rbase + lane * 4];
  const float4 yv = *(const float4*)&y[rbase + lane * 4];
  float sxx = xv.x * xv.x + xv.y * xv.y + xv.z * xv.z + xv.w * xv.w;
  float syy = yv.x * yv.x + yv.y * yv.y + yv.z * yv.z + yv.w * yv.w;
  float sxy = xv.x * yv.x + xv.y * yv.y + xv.z * yv.z + xv.w * yv.w;
#pragma unroll
  for (int o = 1; o < 64; o <<= 1) {
    sxx += __shfl_xor(sxx, o, 64);
    syy += __shfl_xor(syy, o, 64);
    sxy += __shfl_xor(sxy, o, 64);
  }
  const float ix = 1.0f / sqrtf(sxx);
  const float iy = 1.0f / sqrtf(syy);
  if (lane == 0) {
    dd[i] = sxy * ix * iy;
    cnt[i] = 0;                                   // re-zero every call
    if (i == 0) loss_accum[0] = 0.0f;
  }
  const float xs[4] = {xv.x * ix, xv.y * ix, xv.z * ix, xv.w * ix};
  const float ys[4] = {yv.x * iy, yv.y * iy, yv.z * iy, yv.w * iy};
  bf16x4 xh, xl, yh, yl;
#pragma unroll
  for (int e = 0; e < 4; ++e) {
    const __bf16 h = (__bf16)xs[e];
    xh[e] = h; xl[e] = (__bf16)(xs[e] - (float)h);
    const __bf16 g = (__bf16)ys[e];
    yh[e] = g; yl[e] = (__bf16)(ys[e] - (float)g);
  }
  *(bf16x4*)&Xh[rbase + lane * 4] = xh;
  *(bf16x4*)&Xl[rbase + lane * 4] = xl;
  *(bf16x4*)&Yh[rbase + lane * 4] = yh;
  *(bf16x4*)&Yl[rbase + lane * 4] = yl;
}

// ---- 256x256-tile MFMA GEMM, 8 waves, 4-deep LDS ring, counted vmcnt ----
__global__ __launch_bounds__(512, 2) void gemm_mfma(
    const __bf16* __restrict__ Xh, const __bf16* __restrict__ Xl,
    const __bf16* __restrict__ Yh, const __bf16* __restrict__ Yl,
    const float* __restrict__ dd,
    float* __restrict__ loss_accum, int* __restrict__ cnt) {
  __shared__ __bf16 sAB[4][2][256][32];   // [ring buf][A/B][row][K32] = 128 KB
  __shared__ int c_loc[256];
  __shared__ float lred[8];

  const int tid = threadIdx.x;
  // XCD-chunked 2D order: each XCD's 32 concurrent blocks = 4 bi x 8 bj (2MB L2 set)
  const int bid = blockIdx.x;
  const int xcd = bid & 7, idx = bid >> 3;           // 1024 % 8 == 0: bijective
  const int bi = xcd * 4 + (idx & 3);
  const int bj = (idx >> 5) * 8 + ((idx >> 2) & 7);
  const int row0 = bi * 256, col0 = bj * 256;

  const int lane = tid & 63, wid = tid >> 6;
  const int wr = wid >> 2, wc = wid & 3;             // wave -> 128x64 output tile
  const int lr = lane & 15, lkc = lane >> 4;

  if (tid < 256) c_loc[tid] = 0;

  // staging geometry: thread covers 16B-chunk tid and tid+512 of each 16KB half;
  // chunk position p is stored pre-swizzled: fetch global chunk (p&3)^((p>>3)&3)
  const int rowl = tid >> 2;
  const int swz = (tid & 3) ^ ((tid >> 3) & 3);
  const size_t offA0 = (size_t)(row0 + rowl) * (ND * 2) + swz * 16;
  const size_t offB0 = (size_t)(col0 + rowl) * (ND * 2) + swz * 16;
  char* const lds0 = (char*)&sAB[0][0][0][0];

  f32x4 acc[8][4];
#pragma unroll
  for (int m = 0; m < 8; ++m)
#pragma unroll
    for (int n = 0; n < 4; ++n) acc[m][n] = (f32x4)(0.0f);

  auto stage = [&](int t) {
    const char* pa = (const char*)((t >= 8 && t < 16) ? Xl : Xh) + (t & 7) * 64;
    const char* pb = (const char*)((t >= 16) ? Yl : Yh) + (t & 7) * 64;
    char* lb = lds0 + (t & 3) * 32768;
    gload16(pa + offA0,         lb + tid * 16);
    gload16(pa + offA0 + 65536, lb + 8192 + tid * 16);
    gload16(pb + offB0,         lb + 16384 + tid * 16);
    gload16(pb + offB0 + 65536, lb + 24576 + tid * 16);
  };

  const int cko = (lkc ^ ((lr >> 1) & 3)) * 8;   // swizzled k-chunk (2-way = free)
  const int arow = wr * 128 + lr;
  const int brow = wc * 64 + lr;

#pragma unroll
  for (int t = 0; t < 3; ++t) stage(t);          // prologue: 3 tiles in flight

#pragma unroll
  for (int t = 0; t < NT; ++t) {
    if (t + 3 < NT) stage(t + 3);                // ring slot read-complete since t-1
    __builtin_amdgcn_sched_barrier(0);
    // own tile-t loads landed (12 newer stay in flight), then publish to all waves
    if (t < NT - 3)       asm volatile("s_waitcnt vmcnt(12)\n\ts_barrier" ::: "memory");
    else if (t == NT - 3) asm volatile("s_waitcnt vmcnt(8)\n\ts_barrier" ::: "memory");
    else if (t == NT - 2) asm volatile("s_waitcnt vmcnt(4)\n\ts_barrier" ::: "memory");
    else                  asm volatile("s_waitcnt vmcnt(0)\n\ts_barrier" ::: "memory");

    const int b = t & 3;
    bf16x8 bf[4], af[8];
#pragma unroll
    for (int n = 0; n < 4; ++n) bf[n] = *(const bf16x8*)&sAB[b][1][brow + n * 16][cko];
#pragma unroll
    for (int m = 0; m < 8; ++m) af[m] = *(const bf16x8*)&sAB[b][0][arow + m * 16][cko];

    __builtin_amdgcn_s_setprio(1);
#pragma unroll
    for (int m = 0; m < 4; ++m)
#pragma unroll
      for (int n = 0; n < 4; ++n)
        acc[m][n] = __builtin_amdgcn_mfma_f32_16x16x32_bf16(af[m], bf[n], acc[m][n], 0, 0, 0);
    __builtin_amdgcn_s_setprio(0);
    asm volatile("s_barrier" ::: "memory");      // phase lockstep
    __builtin_amdgcn_s_setprio(1);
#pragma unroll
    for (int m = 4; m < 8; ++m)
#pragma unroll
      for (int n = 0; n < 4; ++n)
        acc[m][n] = __builtin_amdgcn_mfma_f32_16x16x32_bf16(af[m], bf[n], acc[m][n], 0, 0, 0);
    __builtin_amdgcn_s_setprio(0);
    asm volatile("s_barrier" ::: "memory");      // all reads of slot b complete
  }

  // ---- epilogue: hinge loss + rank counts (C/D: col=lane&15, row=(lane>>4)*4+q) ----
  float djv[4];
#pragma unroll
  for (int n = 0; n < 4; ++n) djv[n] = dd[col0 + wc * 64 + n * 16 + lr];

  float lsum = 0.f;
#pragma unroll
  for (int m = 0; m < 8; ++m) {
    const int rbase = wr * 128 + m * 16 + lkc * 4;
#pragma unroll
    for (int q = 0; q < 4; ++q) {
      const int gi = row0 + rbase + q;
      const float dival = dd[gi];
      int cl = 0;
#pragma unroll
      for (int n = 0; n < 4; ++n) {
        const int gj = col0 + wc * 64 + n * 16 + lr;
        const float s = acc[m][n][q];
        if (gi != gj) {   // diagonal excluded from BOTH loss and count
          lsum += fmaxf(0.f, s - dival + DELTA_F) + fmaxf(0.f, s - djv[n] + DELTA_F);
          cl += (s > dival) ? 1 : 0;
        }
      }
      cl += __shfl_xor(cl, 1, 64);
      cl += __shfl_xor(cl, 2, 64);
      cl += __shfl_xor(cl, 4, 64);
      cl += __shfl_xor(cl, 8, 64);
      if (lr == 0) atomicAdd(&c_loc[rbase + q], cl);
    }
  }

#pragma unroll
  for (int o = 32; o > 0; o >>= 1) lsum += __shfl_down(lsum, o, 64);
  if (lane == 0) lred[wid] = lsum;
  __syncthreads();
  if (tid == 0) {
    float s = 0.f;
#pragma unroll
    for (int w = 0; w < 8; ++w) s += lred[w];
    atomicAdd(loss_accum, s);
  }
  if (tid < 256) atomicAdd(&cnt[row0 + tid], c_loc[tid]);
}

// ---- finalize: loss scale + recall/ndcg from rank counts ----
__global__ __launch_bounds__(256) void finalize_k(
    const float* __restrict__ loss_accum, const int* __restrict__ cnt,
    float* __restrict__ out) {
  const int t = threadIdx.x;
  float a6[6] = {0.f, 0.f, 0.f, 0.f, 0.f, 0.f};
  for (int i = t; i < NB; i += 256) {
    const int c = cnt[i];
    if (c < 10) {
      const float w = 0.69314718055994531f / logf(2.0f + (float)c);
      a6[2] += 1.f; a6[5] += w;
      if (c < 5) { a6[1] += 1.f; a6[4] += w; }
      if (c < 1) { a6[0] += 1.f; a6[3] += w; }
    }
  }
  __shared__ float red[6][4];
#pragma unroll
  for (int j = 0; j < 6; ++j) {
    float v = a6[j];
#pragma unroll
    for (int o = 32; o > 0; o >>= 1) v += __shfl_down(v, o, 64);
    if ((t & 63) == 0) red[j][t >> 6] = v;
  }
  __syncthreads();
  if (t == 0) {
    out[0] = loss_accum[0] / (float)NB;
#pragma unroll
    for (int j = 0; j < 6; ++j)
      out[1 + j] = red[j][0] + red[j][1] + red[j][2] + red[j][3];
  }
}

extern "C" void kernel_launch(void* const* d_in, const int* in_sizes, int n_in,
                              void* d_out, int out_size, void* d_ws, size_t ws_size,
                              hipStream_t stream) {
  const float* x = (const float*)d_in[0];
  const float* y = (const float*)d_in[1];
  float* out = (float*)d_out;

  char* ws = (char*)d_ws;
  float* loss_accum = (float*)ws;                    // 4 B
  int* cnt = (int*)(ws + 256);                       // 32 KB
  float* dd = (float*)(ws + 256 + 32768);            // 32 KB

  const size_t splitOff = 256 + 2 * 32768;           // 16B-aligned
  const size_t matB = (size_t)NB * ND * 2;           // 4 MB per bf16 matrix
  __bf16* Xh = (__bf16*)(ws + splitOff);
  __bf16* Xl = (__bf16*)(ws + splitOff + matB);
  __bf16* Yh = (__bf16*)(ws + splitOff + 2 * matB);
  __bf16* Yl = (__bf16*)(ws + splitOff + 3 * matB);

  hipLaunchKernelGGL(normalize_split_k, dim3(NB / 4), dim3(256), 0, stream,
                     x, y, Xh, Xl, Yh, Yl, dd, loss_accum, cnt);
  hipLaunchKernelGGL(gemm_mfma, dim3(1024), dim3(512), 0, stream,
                     Xh, Xl, Yh, Yl, dd, loss_accum, cnt);
  hipLaunchKernelGGL(finalize_k, dim3(1), dim3(256), 0, stream, loss_accum, cnt, out);
}

// Round 5
// 139.632 us; speedup vs baseline: 1.2045x; 1.2045x over previous
//
#include <hip/hip_runtime.h>
#include <math.h>

#define NB 8192
#define ND 256
#define DELTA_F 0.2f

typedef __attribute__((ext_vector_type(8))) __bf16 bf16x8;
typedef __attribute__((ext_vector_type(4))) __bf16 bf16x4;
typedef __attribute__((ext_vector_type(4))) float f32x4;

__device__ __forceinline__ void gload16(const void* g, void* l) {
  __builtin_amdgcn_global_load_lds(
      (const __attribute__((address_space(1))) void*)g,
      (__attribute__((address_space(3))) void*)l, 16, 0, 0);
}

// ---- prep: wave-per-row norms, diag sim, hi/lo bf16 splits; zeroes cnt/loss ----
__global__ __launch_bounds__(256) void normalize_split_k(
    const float* __restrict__ x, const float* __restrict__ y,
    __bf16* __restrict__ Xh, __bf16* __restrict__ Xl,
    __bf16* __restrict__ Yh, __bf16* __restrict__ Yl,
    float* __restrict__ dd, float* __restrict__ loss_accum, int* __restrict__ cnt) {
  const int w = threadIdx.x >> 6, lane = threadIdx.x & 63;
  const int i = blockIdx.x * 4 + w;
  const size_t rbase = (size_t)i * ND;
  const float4 xv = *(const float4*)&x[rbase + lane * 4];
  const float4 yv = *(const float4*)&y[rbase + lane * 4];
  float sxx = xv.x * xv.x + xv.y * xv.y + xv.z * xv.z + xv.w * xv.w;
  float syy = yv.x * yv.x + yv.y * yv.y + yv.z * yv.z + yv.w * yv.w;
  float sxy = xv.x * yv.x + xv.y * yv.y + xv.z * yv.z + xv.w * yv.w;
#pragma unroll
  for (int o = 1; o < 64; o <<= 1) {
    sxx += __shfl_xor(sxx, o, 64);
    syy += __shfl_xor(syy, o, 64);
    sxy += __shfl_xor(sxy, o, 64);
  }
  const float ix = 1.0f / sqrtf(sxx);
  const float iy = 1.0f / sqrtf(syy);
  if (lane == 0) {
    dd[i] = sxy * ix * iy;
    cnt[i] = 0;                                   // re-zero every call
    if (i == 0) loss_accum[0] = 0.0f;
  }
  const float xs[4] = {xv.x * ix, xv.y * ix, xv.z * ix, xv.w * ix};
  const float ys[4] = {yv.x * iy, yv.y * iy, yv.z * iy, yv.w * iy};
  bf16x4 xh, xl, yh, yl;
#pragma unroll
  for (int e = 0; e < 4; ++e) {
    const __bf16 h = (__bf16)xs[e];
    xh[e] = h; xl[e] = (__bf16)(xs[e] - (float)h);
    const __bf16 g = (__bf16)ys[e];
    yh[e] = g; yl[e] = (__bf16)(ys[e] - (float)g);
  }
  *(bf16x4*)&Xh[rbase + lane * 4] = xh;
  *(bf16x4*)&Xl[rbase + lane * 4] = xl;
  *(bf16x4*)&Yh[rbase + lane * 4] = yh;
  *(bf16x4*)&Yl[rbase + lane * 4] = yl;
}

// ---- 256x256-tile MFMA GEMM, 8 waves, ring-2 dbuf, counted vmcnt(8),
//      all 3 split-terms per staged tile (64 KB staged per 96 MFMAs/wave) ----
__global__ __launch_bounds__(512, 2) void gemm_mfma(
    const __bf16* __restrict__ Xh, const __bf16* __restrict__ Xl,
    const __bf16* __restrict__ Yh, const __bf16* __restrict__ Yl,
    const float* __restrict__ dd,
    float* __restrict__ loss_accum, int* __restrict__ cnt) {
  __shared__ __bf16 sAB[2][4][256][32];   // [slot][Ah,Al,Bh,Bl][row][k] = 128 KB
  __shared__ int c_loc[256];
  __shared__ float lred[8];

  const int tid = threadIdx.x;
  // XCD-chunked 2D order: each XCD's 32 concurrent blocks = 4 bi x 8 bj
  const int bid = blockIdx.x;
  const int xcd = bid & 7, idx = bid >> 3;           // 1024 % 8 == 0: bijective
  const int bi = xcd * 4 + (idx & 3);
  const int bj = (idx >> 5) * 8 + ((idx >> 2) & 7);
  const int row0 = bi * 256, col0 = bj * 256;

  const int lane = tid & 63, wid = tid >> 6;
  const int wr = wid >> 2, wc = wid & 3;             // wave -> 128x64 output tile
  const int lr = lane & 15, lkc = lane >> 4;

  if (tid < 256) c_loc[tid] = 0;

  // staging: thread covers (row = tid>>2, chunk pos = tid&3); stored chunk is
  // pre-swizzled: fetch global chunk (tid&3) ^ ((row>>1)&3). Verified r3/r4.
  const int rowl = tid >> 2;
  const int swz = (tid & 3) ^ ((tid >> 3) & 3);
  const char* const pAh = (const char*)Xh + (size_t)(row0 + rowl) * 512 + swz * 16;
  const char* const pAl = (const char*)Xl + (size_t)(row0 + rowl) * 512 + swz * 16;
  const char* const pBh = (const char*)Yh + (size_t)(col0 + rowl) * 512 + swz * 16;
  const char* const pBl = (const char*)Yl + (size_t)(col0 + rowl) * 512 + swz * 16;
  char* const lds0 = (char*)&sAB[0][0][0][0];

  f32x4 acc[8][4];
#pragma unroll
  for (int m = 0; m < 8; ++m)
#pragma unroll
    for (int n = 0; n < 4; ++n) acc[m][n] = (f32x4)(0.0f);

  auto stage = [&](int t) {   // t is compile-time (unrolled)
    char* lb = lds0 + (t & 1) * 65536;
    const int ko = t * 64;    // 32 bf16 of K per step
    gload16(pAh + ko,         lb + tid * 16);
    gload16(pAh + ko + 65536, lb +  8192 + tid * 16);
    gload16(pAl + ko,         lb + 16384 + tid * 16);
    gload16(pAl + ko + 65536, lb + 24576 + tid * 16);
    gload16(pBh + ko,         lb + 32768 + tid * 16);
    gload16(pBh + ko + 65536, lb + 40960 + tid * 16);
    gload16(pBl + ko,         lb + 49152 + tid * 16);
    gload16(pBl + ko + 65536, lb + 57344 + tid * 16);
  };

  const int cko = (lkc ^ ((lr >> 1) & 3)) * 8;   // swizzled k-chunk (2-way = free)

  stage(0);
#pragma unroll
  for (int t = 0; t < 8; ++t) {
    if (t < 7) stage(t + 1);                     // issue-early into other slot
    // own tile-t loads landed (8 newer stay in flight); publish to all waves
    if (t < 7) asm volatile("s_waitcnt vmcnt(8)\n\ts_barrier" ::: "memory");
    else       asm volatile("s_waitcnt vmcnt(0)\n\ts_barrier" ::: "memory");

    const int b = t & 1;
    bf16x8 bh4[4], bl4[4];
#pragma unroll
    for (int n = 0; n < 4; ++n) {
      bh4[n] = *(const bf16x8*)&sAB[b][2][wc * 64 + n * 16 + lr][cko];
      bl4[n] = *(const bf16x8*)&sAB[b][3][wc * 64 + n * 16 + lr][cko];
    }
#pragma unroll
    for (int half = 0; half < 2; ++half) {       // m-split keeps VGPR demand low
      bf16x8 ah4[4], al4[4];
#pragma unroll
      for (int m = 0; m < 4; ++m) {
        const int r = wr * 128 + (half * 4 + m) * 16 + lr;
        ah4[m] = *(const bf16x8*)&sAB[b][0][r][cko];
        al4[m] = *(const bf16x8*)&sAB[b][1][r][cko];
      }
      __builtin_amdgcn_s_setprio(1);
#pragma unroll
      for (int m = 0; m < 4; ++m)
#pragma unroll
        for (int n = 0; n < 4; ++n) {
          f32x4 a = acc[half * 4 + m][n];
          a = __builtin_amdgcn_mfma_f32_16x16x32_bf16(ah4[m], bh4[n], a, 0, 0, 0);
          a = __builtin_amdgcn_mfma_f32_16x16x32_bf16(ah4[m], bl4[n], a, 0, 0, 0);
          a = __builtin_amdgcn_mfma_f32_16x16x32_bf16(al4[m], bh4[n], a, 0, 0, 0);
          acc[half * 4 + m][n] = a;
        }
      __builtin_amdgcn_s_setprio(0);
    }
  }

  // ---- epilogue: hinge loss + rank counts (C/D: col=lane&15, row=(lane>>4)*4+q) ----
  float djv[4];
#pragma unroll
  for (int n = 0; n < 4; ++n) djv[n] = dd[col0 + wc * 64 + n * 16 + lr];

  float lsum = 0.f;
#pragma unroll
  for (int m = 0; m < 8; ++m) {
    const int rbase = wr * 128 + m * 16 + lkc * 4;
#pragma unroll
    for (int q = 0; q < 4; ++q) {
      const int gi = row0 + rbase + q;
      const float dival = dd[gi];
      int cl = 0;
#pragma unroll
      for (int n = 0; n < 4; ++n) {
        const int gj = col0 + wc * 64 + n * 16 + lr;
        const float s = acc[m][n][q];
        if (gi != gj) {   // diagonal excluded from BOTH loss and count
          lsum += fmaxf(0.f, s - dival + DELTA_F) + fmaxf(0.f, s - djv[n] + DELTA_F);
          cl += (s > dival) ? 1 : 0;
        }
      }
      cl += __shfl_xor(cl, 1, 64);
      cl += __shfl_xor(cl, 2, 64);
      cl += __shfl_xor(cl, 4, 64);
      cl += __shfl_xor(cl, 8, 64);
      if (lr == 0) atomicAdd(&c_loc[rbase + q], cl);
    }
  }

#pragma unroll
  for (int o = 32; o > 0; o >>= 1) lsum += __shfl_down(lsum, o, 64);
  if (lane == 0) lred[wid] = lsum;
  __syncthreads();
  if (tid == 0) {
    float s = 0.f;
#pragma unroll
    for (int w = 0; w < 8; ++w) s += lred[w];
    atomicAdd(loss_accum, s);
  }
  if (tid < 256) atomicAdd(&cnt[row0 + tid], c_loc[tid]);
}

// ---- finalize: loss scale + recall/ndcg from rank counts ----
__global__ __launch_bounds__(256) void finalize_k(
    const float* __restrict__ loss_accum, const int* __restrict__ cnt,
    float* __restrict__ out) {
  const int t = threadIdx.x;
  float a6[6] = {0.f, 0.f, 0.f, 0.f, 0.f, 0.f};
  for (int i = t; i < NB; i += 256) {
    const int c = cnt[i];
    if (c < 10) {
      const float w = 0.69314718055994531f / logf(2.0f + (float)c);
      a6[2] += 1.f; a6[5] += w;
      if (c < 5) { a6[1] += 1.f; a6[4] += w; }
      if (c < 1) { a6[0] += 1.f; a6[3] += w; }
    }
  }
  __shared__ float red[6][4];
#pragma unroll
  for (int j = 0; j < 6; ++j) {
    float v = a6[j];
#pragma unroll
    for (int o = 32; o > 0; o >>= 1) v += __shfl_down(v, o, 64);
    if ((t & 63) == 0) red[j][t >> 6] = v;
  }
  __syncthreads();
  if (t == 0) {
    out[0] = loss_accum[0] / (float)NB;
#pragma unroll
    for (int j = 0; j < 6; ++j)
      out[1 + j] = red[j][0] + red[j][1] + red[j][2] + red[j][3];
  }
}

extern "C" void kernel_launch(void* const* d_in, const int* in_sizes, int n_in,
                              void* d_out, int out_size, void* d_ws, size_t ws_size,
                              hipStream_t stream) {
  const float* x = (const float*)d_in[0];
  const float* y = (const float*)d_in[1];
  float* out = (float*)d_out;

  char* ws = (char*)d_ws;
  float* loss_accum = (float*)ws;                    // 4 B
  int* cnt = (int*)(ws + 256);                       // 32 KB
  float* dd = (float*)(ws + 256 + 32768);            // 32 KB

  const size_t splitOff = 256 + 2 * 32768;           // 16B-aligned
  const size_t matB = (size_t)NB * ND * 2;           // 4 MB per bf16 matrix
  __bf16* Xh = (__bf16*)(ws + splitOff);
  __bf16* Xl = (__bf16*)(ws + splitOff + matB);
  __bf16* Yh = (__bf16*)(ws + splitOff + 2 * matB);
  __bf16* Yl = (__bf16*)(ws + splitOff + 3 * matB);

  hipLaunchKernelGGL(normalize_split_k, dim3(NB / 4), dim3(256), 0, stream,
                     x, y, Xh, Xl, Yh, Yl, dd, loss_accum, cnt);
  hipLaunchKernelGGL(gemm_mfma, dim3(1024), dim3(512), 0, stream,
                     Xh, Xl, Yh, Yl, dd, loss_accum, cnt);
  hipLaunchKernelGGL(finalize_k, dim3(1), dim3(256), 0, stream, loss_accum, cnt, out);
}